// Round 2
// baseline (1155.976 us; speedup 1.0000x reference)
//
#include <hip/hip_runtime.h>
#include <hip/hip_bf16.h>
#include <math.h>

// ---- problem constants ----
#define CB 8
#define CT 6
#define CN 24
#define CL 1024
#define CD 512
#define CH 8
#define CDH 64
#define CTN 144     // T*N
#define CTL 6144    // T*L
#define CMT 96      // CTL/64 m-tiles
#define CEPS 1e-5f

typedef __bf16 bf16x8 __attribute__((ext_vector_type(8)));
typedef float  f32x4  __attribute__((ext_vector_type(4)));

#define MFMA16(a,b,c) __builtin_amdgcn_mfma_f32_16x16x32_bf16(a,b,c,0,0,0)

union BF8 { unsigned short s[8]; bf16x8 v; };

static __device__ __forceinline__ unsigned short f2bf(float x){
    union { float f; unsigned u; } c; c.f = x;
    return (unsigned short)((c.u + 0x7FFFu + ((c.u >> 16) & 1u)) >> 16);
}

static __device__ __forceinline__ bf16x8 cvt8(const float* __restrict__ p){
    const f32x4* q = (const f32x4*)p;
    f32x4 v0 = q[0], v1 = q[1];
    BF8 r;
    r.s[0]=f2bf(v0[0]); r.s[1]=f2bf(v0[1]); r.s[2]=f2bf(v0[2]); r.s[3]=f2bf(v0[3]);
    r.s[4]=f2bf(v1[0]); r.s[5]=f2bf(v1[1]); r.s[6]=f2bf(v1[2]); r.s[7]=f2bf(v1[3]);
    return r.v;
}

static __device__ __forceinline__ bf16x8 ldbf8(const unsigned short* __restrict__ p){
    return *(const bf16x8*)p;
}

#define GL16(gp, lp) __builtin_amdgcn_global_load_lds((const unsigned int*)(gp), (unsigned int*)(lp), 16, 0, 0)

// ---- convert weights to bf16 ----
__global__ void cvt_w_kernel(const float* __restrict__ w0, const float* __restrict__ w1,
                             const float* __restrict__ w2, const float* __restrict__ w3,
                             unsigned short* __restrict__ o0, unsigned short* __restrict__ o1,
                             unsigned short* __restrict__ o2, unsigned short* __restrict__ o3){
    int i = blockIdx.x*blockDim.x + threadIdx.x;
    const int n = CD*CD;
    if      (i < n)   o0[i]       = f2bf(w0[i]);
    else if (i < 2*n) o1[i-n]     = f2bf(w1[i-n]);
    else if (i < 3*n) o2[i-2*n]   = f2bf(w2[i-2*n]);
    else if (i < 4*n) o3[i-3*n]   = f2bf(w3[i-3*n]);
}

// ---- convert fp32 -> bf16, 8 elems/thread ----
__global__ void cvt_x_kernel(const float* __restrict__ src, unsigned short* __restrict__ dst, int n8){
    int i = blockIdx.x*blockDim.x + threadIdx.x;
    if (i >= n8) return;
    *(bf16x8*)(dst + (size_t)i*8) = cvt8(src + (size_t)i*8);
}

// ---- m97-style GEMM: Y = A(bf16)[rows x 512] @ W(bf16)[512 x 512]^T ----
// MODE 0: out bf16 [((bb*H+h)*posPer + pos)*64 + dh]   (qp, kp)
// MODE 1: out bf16 [((bb*H+h)*64 + dh)*posPer + pos]   (vpT)
// MODE 2: out fp32 [row*512 + col]                     (final out)
template<int MODE>
__global__ __launch_bounds__(256) void gemm_m97(
    const unsigned short* __restrict__ A, const unsigned short* __restrict__ W,
    void* __restrict__ outv, int posPer, int rowoff, float scale)
{
    __shared__ union {
        struct { unsigned short As[128*32]; unsigned short Bs[128*32]; } s;
        float epi[32][129];
    } sm;

    // bijective XCD swizzle (gridDim.x == 4 always)
    int nwg = gridDim.x*gridDim.y;
    int id  = blockIdx.y*gridDim.x + blockIdx.x;
    int q8 = nwg >> 3, r8 = nwg & 7;
    int xcd = id & 7, rk = id >> 3;
    int swz = (xcd < r8 ? xcd*(q8+1) : r8*(q8+1) + (xcd-r8)*q8) + rk;
    int ctile = swz & 3;
    int bt    = swz >> 2;

    int lane = threadIdx.x & 63, wave = threadIdx.x >> 6;
    int wr = wave >> 1, wc = wave & 1;

    const unsigned short* Abase = A + (size_t)bt*128*CD;
    const unsigned short* Wbase = W + (size_t)ctile*128*CD;
    int sr = threadIdx.x >> 2, sc = (threadIdx.x & 3)*8;
    const unsigned short* ga = Abase + (size_t)sr*CD + sc;
    const unsigned short* gb = Wbase + (size_t)sr*CD + sc;
    unsigned short* lA = sm.s.As + wave*512;
    unsigned short* lB = sm.s.Bs + wave*512;

    f32x4 acc[4][4] = {};

    for (int k0 = 0; k0 < CD; k0 += 32) {
        GL16(ga + k0,          lA);
        GL16(ga + 64*CD + k0,  lA + 2048);
        GL16(gb + k0,          lB);
        GL16(gb + 64*CD + k0,  lB + 2048);
        __syncthreads();
        bf16x8 af[4], bf[4];
        #pragma unroll
        for (int mf = 0; mf < 4; ++mf)
            af[mf] = *(const bf16x8*)&sm.s.As[(wr*64 + mf*16 + (lane&15))*32 + (lane>>4)*8];
        #pragma unroll
        for (int nf = 0; nf < 4; ++nf)
            bf[nf] = *(const bf16x8*)&sm.s.Bs[(wc*64 + nf*16 + (lane&15))*32 + (lane>>4)*8];
        #pragma unroll
        for (int mf = 0; mf < 4; ++mf)
            #pragma unroll
            for (int nf = 0; nf < 4; ++nf)
                acc[mf][nf] = MFMA16(af[mf], bf[nf], acc[mf][nf]);
        __syncthreads();
    }

    // epilogue: 4 passes of 32 rows through LDS (fp32, padded 129 -> conflict-free)
    unsigned short* outu = (unsigned short*)outv;
    float* outf = (float*)outv;
    for (int p = 0; p < 4; ++p) {
        if (wr == (p >> 1)) {
            #pragma unroll
            for (int mh = 0; mh < 2; ++mh) {
                int mf = (p&1)*2 + mh;
                #pragma unroll
                for (int nf = 0; nf < 4; ++nf)
                    #pragma unroll
                    for (int r = 0; r < 4; ++r)
                        sm.epi[mh*16 + 4*(lane>>4) + r][wc*64 + nf*16 + (lane&15)] = acc[mf][nf][r]*scale;
            }
        }
        __syncthreads();
        if (MODE == 1) {
            #pragma unroll
            for (int i = 0; i < 16; ++i) {
                int c2 = i*8 + wave*2 + (lane>>5);
                int gr = rowoff + bt*128 + p*32 + (lane & 31);
                int bb = gr / posPer, pos = gr - bb*posPer;
                int hh = ctile*2 + (c2>>6), dh = c2 & 63;
                outu[((size_t)(bb*CH + hh)*64 + dh)*posPer + pos] = f2bf(sm.epi[lane&31][c2]);
            }
        } else {
            #pragma unroll
            for (int i = 0; i < 16; ++i) {
                int task = i*4 + wave;     // 0..63: (lr, ch)
                int lr = task >> 1, ch = task & 1;
                float val = sm.epi[lr][ch*64 + lane];
                int gr = rowoff + bt*128 + p*32 + lr;
                if (MODE == 2) {
                    outf[(size_t)gr*CD + ctile*128 + ch*64 + lane] = val;
                } else {
                    int bb = gr / posPer, pos = gr - bb*posPer;
                    int hh = ctile*2 + ch;
                    outu[((size_t)(bb*CH + hh)*posPer + pos)*64 + lane] = f2bf(val);
                }
            }
        }
        __syncthreads();
    }
}

// ---- scores: S = qp @ kp^T for one (b,h), 144 x 64 m-tile ----
template<int PHASE>
__global__ __launch_bounds__(256) void scores_kernel(
    const unsigned short* __restrict__ qp, const unsigned short* __restrict__ kp,
    const int* __restrict__ mask,
    float* __restrict__ pmax, float* __restrict__ psum,
    const float* __restrict__ gmax, const float* __restrict__ gsum,
    float* __restrict__ avis, float* __restrict__ rowpart)
{
    __shared__ float S[CTN][65];
    int mt = blockIdx.x;
    int h = blockIdx.y, b = blockIdx.z;
    int lane = threadIdx.x & 63, wave = threadIdx.x >> 6;
    const unsigned short* qbase = qp + (size_t)(b*CH + h)*CTN*64;
    const unsigned short* kbase = kp + (size_t)(b*CH + h)*CTL*64;
    int koff = 8*(lane>>4);
    f32x4 acc[3][4] = {};
    for (int k0 = 0; k0 < 64; k0 += 32) {
        bf16x8 bfr[4];
        #pragma unroll
        for (int cf = 0; cf < 4; ++cf)
            bfr[cf] = ldbf8(kbase + (size_t)(mt*64 + cf*16 + (lane&15))*64 + k0 + koff);
        #pragma unroll
        for (int i = 0; i < 3; ++i) {
            int rt = wave + 4*i;
            if (rt < 9) {
                bf16x8 a = ldbf8(qbase + (size_t)(rt*16 + (lane&15))*64 + k0 + koff);
                #pragma unroll
                for (int cf = 0; cf < 4; ++cf)
                    acc[i][cf] = MFMA16(a, bfr[cf], acc[i][cf]);
            }
        }
    }
    #pragma unroll
    for (int i = 0; i < 3; ++i) {
        int rt = wave + 4*i;
        if (rt < 9) {
            #pragma unroll
            for (int cf = 0; cf < 4; ++cf)
                #pragma unroll
                for (int r = 0; r < 4; ++r)
                    S[rt*16 + 4*(lane>>4) + r][cf*16 + (lane&15)] = acc[i][cf][r];
        }
    }
    __syncthreads();
    int mg0 = mt*64;
    if (PHASE == 0) {
        for (int task = threadIdx.x; task < CT*64; task += 256) {
            int t = task >> 6, ml = task & 63;
            int mg = mg0 + ml;
            float mx = -INFINITY;
            float sv[24];
            #pragma unroll
            for (int i = 0; i < 24; ++i) {
                int tn = t*24 + i;
                bool msk = mask[(size_t)tn*CTL + mg] != 0;
                float s = msk ? -INFINITY : S[tn][ml];
                sv[i] = s;
                mx = fmaxf(mx, s);
            }
            float sum = 0.f;
            if (mx > -INFINITY) {
                #pragma unroll
                for (int i = 0; i < 24; ++i)
                    if (sv[i] > -INFINITY) sum += __expf(sv[i] - mx);
            }
            size_t idx = ((size_t)(b*CH + h)*CT + t)*CTL + mg;
            pmax[idx] = mx; psum[idx] = sum;
        }
    } else {
        for (int it = 0; it < 36; ++it) {
            int row = 4*it + wave;
            int mg = mg0 + lane;
            int t = row / 24;
            size_t gidx = ((size_t)b*CT + t)*CTL + mg;
            float g = gmax[gidx], gs = gsum[gidx];
            bool msk = mask[(size_t)row*CTL + mg] != 0;
            float a = (!msk && gs > 0.f) ? __expf(S[row][lane] - g) / gs : 0.f;
            avis[((size_t)(b*CH + h)*CTN + row)*CTL + mg] = a;
            float s = a;
            #pragma unroll
            for (int o = 1; o < 64; o <<= 1) s += __shfl_xor(s, o);
            if (lane == 0)
                rowpart[((size_t)(b*CH + h)*CTN + row)*CMT + mt] = s;
        }
    }
}

// ---- combine partial softmax stats across heads ----
__global__ void combine_kernel(const float* __restrict__ pmax, const float* __restrict__ psum,
                               float* __restrict__ gmax, float* __restrict__ gsum){
    size_t i = (size_t)blockIdx.x*blockDim.x + threadIdx.x;
    if (i >= (size_t)CB*CT*CTL) return;
    int m = (int)(i % CTL);
    size_t bt = i / CTL;
    int t = (int)(bt % CT), b = (int)(bt / CT);
    float pm[CH], ps[CH];
    float mx = -INFINITY;
    #pragma unroll
    for (int h = 0; h < CH; ++h) {
        size_t idx = ((size_t)(b*CH + h)*CT + t)*CTL + m;
        pm[h] = pmax[idx]; ps[h] = psum[idx];
        mx = fmaxf(mx, pm[h]);
    }
    float s = 0.f;
    if (mx > -INFINITY) {
        #pragma unroll
        for (int h = 0; h < CH; ++h)
            if (pm[h] > -INFINITY) s += ps[h]*__expf(pm[h] - mx);
    }
    gmax[i] = mx; gsum[i] = s;
}

// ---- reduce per-tile rowsums ----
__global__ void rowsum_kernel(const float* __restrict__ rowpart, float* __restrict__ rowsum){
    int i = blockIdx.x*blockDim.x + threadIdx.x;
    if (i >= CB*CH*CTN) return;
    float s = 0.f;
    for (int j = 0; j < CMT; ++j) s += rowpart[(size_t)i*CMT + j];
    rowsum[i] = s;
}

// ---- PV split-K: partial[ks] = a[:, ks-chunk] @ vp[ks-chunk, :] ----
__global__ __launch_bounds__(256) void pv_kernel(
    const float* __restrict__ avis, const unsigned short* __restrict__ vpT,
    float* __restrict__ pvpart)
{
    int ks = blockIdx.x;              // 8 chunks of 768
    int h = blockIdx.y, b = blockIdx.z;
    int bh = b*CH + h;
    int wave = threadIdx.x >> 6, lane = threadIdx.x & 63;
    int r0  = (wave == 0) ? 0 : (wave*2 + 1);   // {0,3,5,7}
    int nrt = (wave == 0) ? 3 : 2;
    const float* abase = avis + (size_t)bh*CTN*CTL;
    const unsigned short* vb = vpT + (size_t)bh*64*CTL;
    int koff = 8*(lane>>4);
    f32x4 acc[3][4] = {};
    int m0base = ks*768;
    for (int mm = 0; mm < 768; mm += 32) {
        int m0 = m0base + mm;
        bf16x8 bv[4];
        #pragma unroll
        for (int cf = 0; cf < 4; ++cf)
            bv[cf] = ldbf8(vb + (size_t)(cf*16 + (lane&15))*CTL + m0 + koff);
        #pragma unroll
        for (int i = 0; i < 3; ++i) {
            if (i < nrt) {
                bf16x8 a = cvt8(abase + (size_t)((r0+i)*16 + (lane&15))*CTL + m0 + koff);
                #pragma unroll
                for (int cf = 0; cf < 4; ++cf)
                    acc[i][cf] = MFMA16(a, bv[cf], acc[i][cf]);
            }
        }
    }
    float* pb = pvpart + (size_t)(ks*64 + bh)*CTN*64;
    #pragma unroll
    for (int i = 0; i < 3; ++i) {
        if (i < nrt) {
            #pragma unroll
            for (int cf = 0; cf < 4; ++cf)
                #pragma unroll
                for (int r = 0; r < 4; ++r) {
                    int row = (r0+i)*16 + 4*(lane>>4) + r;
                    pb[row*64 + cf*16 + (lane&15)] = acc[i][cf][r];
                }
        }
    }
}

// ---- reduce PV partials, renormalize, write oh bf16 ----
__global__ void pv_reduce_kernel(const float* __restrict__ pvpart, const float* __restrict__ rowsum,
                                 unsigned short* __restrict__ oh){
    int idx = blockIdx.x*blockDim.x + threadIdx.x;
    if (idx >= CB*CH*CTN*64) return;
    float s = 0.f;
    #pragma unroll
    for (int ks = 0; ks < 8; ++ks)
        s += pvpart[(size_t)ks*(CB*CH*CTN*64) + idx];
    int col = idx & 63;
    int rowbh = idx >> 6;
    int row = rowbh % CTN, bh = rowbh / CTN;
    float inv = 1.f / (rowsum[rowbh] + CEPS);
    int b = bh >> 3, h = bh & 7;
    oh[((size_t)b*CTN + row)*CD + h*64 + col] = f2bf(s*inv);
}

extern "C" void kernel_launch(void* const* d_in, const int* in_sizes, int n_in,
                              void* d_out, int out_size, void* d_ws, size_t ws_size,
                              hipStream_t stream)
{
    const float* q    = (const float*)d_in[0];
    const float* k    = (const float*)d_in[1];
    const float* v    = (const float*)d_in[2];
    const int*   mask = (const int*)  d_in[3];
    const float* Wq   = (const float*)d_in[4];
    const float* Wk   = (const float*)d_in[5];
    const float* Wv   = (const float*)d_in[6];
    const float* Wo   = (const float*)d_in[7];

    float* out0 = (float*)d_out;
    float* avis = out0 + (size_t)CB*CTN*CD;

    char* p = (char*)d_ws;
    auto alloc = [&](size_t bytes) -> char* {
        char* r = p; p += (bytes + 255) & ~(size_t)255; return r;
    };
    unsigned short* Wq_bf = (unsigned short*)alloc((size_t)CD*CD*2);
    unsigned short* Wk_bf = (unsigned short*)alloc((size_t)CD*CD*2);
    unsigned short* Wv_bf = (unsigned short*)alloc((size_t)CD*CD*2);
    unsigned short* Wo_bf = (unsigned short*)alloc((size_t)CD*CD*2);
    unsigned short* qp    = (unsigned short*)alloc((size_t)CB*CH*CTN*64*2);
    unsigned short* kp    = (unsigned short*)alloc((size_t)CB*CH*CTL*64*2);
    unsigned short* vpT   = (unsigned short*)alloc((size_t)CB*CH*64*CTL*2);
    // stats region S (22.41 MB), multi-purpose:
    //   phase 1: xbf chunk buffer (16.78 MB) / qbf (1.18 MB)
    //   phase 2: pmax(9.44) | psum(9.44) | rowpart(3.54)
    //   phase 3: pvpart(18.87, over dead pmax+psum) | rowpart still live until rowsum_kernel
    char* S = alloc((size_t)(CB*CH*CT*CTL*4)*2 + (size_t)CB*CH*CTN*CMT*4);
    unsigned short* xbf = (unsigned short*)S;
    float* pmax    = (float*)S;
    float* psum    = (float*)(S + (size_t)CB*CH*CT*CTL*4);
    float* rowpart = (float*)(S + (size_t)CB*CH*CT*CTL*4*2);
    float* pvpart  = (float*)S;
    float* gmax   = (float*)alloc((size_t)CB*CT*CTL*4);
    float* gsum   = (float*)alloc((size_t)CB*CT*CTL*4);
    float* rowsum = (float*)alloc((size_t)CB*CH*CTN*4);
    unsigned short* oh = (unsigned short*)alloc((size_t)CB*CTN*CD*2);

    // 1. weights -> bf16
    cvt_w_kernel<<<(4*CD*CD + 255)/256, 256, 0, stream>>>(Wq, Wk, Wv, Wo,
                                                          Wq_bf, Wk_bf, Wv_bf, Wo_bf);
    // 2. q projection (q -> bf16 in S, then GEMM)
    cvt_x_kernel<<<(CB*CTN*CD/8 + 255)/256, 256, 0, stream>>>(q, xbf, CB*CTN*CD/8);
    gemm_m97<0><<<dim3(4, CB*CTN/128), 256, 0, stream>>>(xbf, Wq_bf, qp, CTN, 0, 0.125f);
    // 3. k projection, 3 chunks of 16384 rows
    for (int c = 0; c < 3; ++c) {
        cvt_x_kernel<<<(16384*CD/8 + 255)/256, 256, 0, stream>>>(k + (size_t)c*16384*CD, xbf, 16384*CD/8);
        gemm_m97<0><<<dim3(4, 128), 256, 0, stream>>>(xbf, Wk_bf, kp, CTL, c*16384, 1.0f);
    }
    // 4. v projection (transposed output), 3 chunks
    for (int c = 0; c < 3; ++c) {
        cvt_x_kernel<<<(16384*CD/8 + 255)/256, 256, 0, stream>>>(v + (size_t)c*16384*CD, xbf, 16384*CD/8);
        gemm_m97<1><<<dim3(4, 128), 256, 0, stream>>>(xbf, Wv_bf, vpT, CTL, c*16384, 1.0f);
    }
    // 5. scores pass A: partial softmax stats
    scores_kernel<0><<<dim3(CMT, CH, CB), 256, 0, stream>>>(qp, kp, mask,
        pmax, psum, nullptr, nullptr, nullptr, nullptr);
    // 6. combine across heads
    combine_kernel<<<((CB*CT*CTL) + 255)/256, 256, 0, stream>>>(pmax, psum, gmax, gsum);
    // 7. scores pass B: attn_vis + rowsums
    scores_kernel<1><<<dim3(CMT, CH, CB), 256, 0, stream>>>(qp, kp, mask,
        nullptr, nullptr, gmax, gsum, avis, rowpart);
    // 8. rowsum reduce
    rowsum_kernel<<<((CB*CH*CTN) + 255)/256, 256, 0, stream>>>(rowpart, rowsum);
    // 9. PV split-K (pvpart aliases dead pmax/psum)
    pv_kernel<<<dim3(8, CH, CB), 256, 0, stream>>>(avis, vpT, pvpart);
    // 10. reduce partials + renorm
    pv_reduce_kernel<<<((CB*CH*CTN*64) + 255)/256, 256, 0, stream>>>(pvpart, rowsum, oh);
    // 11. output projection
    gemm_m97<2><<<dim3(4, CB*CTN/128), 256, 0, stream>>>(oh, Wo_bf, out0, CD, 0, 1.0f);
}

// Round 3
// 1130.444 us; speedup vs baseline: 1.0226x; 1.0226x over previous
//
#include <hip/hip_runtime.h>
#include <hip/hip_bf16.h>
#include <math.h>

// ---- problem constants ----
#define CB 8
#define CT 6
#define CN 24
#define CL 1024
#define CD 512
#define CH 8
#define CDH 64
#define CTN 144     // T*N
#define CTL 6144    // T*L
#define CEPS 1e-5f

typedef __bf16 bf16x8 __attribute__((ext_vector_type(8)));
typedef float  f32x4  __attribute__((ext_vector_type(4)));

#define MFMA16(a,b,c) __builtin_amdgcn_mfma_f32_16x16x32_bf16(a,b,c,0,0,0)

union BF8 { unsigned short s[8]; bf16x8 v; };

static __device__ __forceinline__ unsigned short f2bf(float x){
    union { float f; unsigned u; } c; c.f = x;
    return (unsigned short)((c.u + 0x7FFFu + ((c.u >> 16) & 1u)) >> 16);
}

static __device__ __forceinline__ bf16x8 cvt8(const float* __restrict__ p){
    const f32x4* q = (const f32x4*)p;
    f32x4 v0 = q[0], v1 = q[1];
    BF8 r;
    r.s[0]=f2bf(v0[0]); r.s[1]=f2bf(v0[1]); r.s[2]=f2bf(v0[2]); r.s[3]=f2bf(v0[3]);
    r.s[4]=f2bf(v1[0]); r.s[5]=f2bf(v1[1]); r.s[6]=f2bf(v1[2]); r.s[7]=f2bf(v1[3]);
    return r.v;
}

static __device__ __forceinline__ bf16x8 ldbf8(const unsigned short* __restrict__ p){
    return *(const bf16x8*)p;
}

#define GL16(gp, lp) __builtin_amdgcn_global_load_lds((const unsigned int*)(gp), (unsigned int*)(lp), 16, 0, 0)

// ---- convert weights to bf16 ----
__global__ void cvt_w_kernel(const float* __restrict__ w0, const float* __restrict__ w1,
                             const float* __restrict__ w2, const float* __restrict__ w3,
                             unsigned short* __restrict__ o0, unsigned short* __restrict__ o1,
                             unsigned short* __restrict__ o2, unsigned short* __restrict__ o3){
    int i = blockIdx.x*blockDim.x + threadIdx.x;
    const int n = CD*CD;
    if      (i < n)   o0[i]       = f2bf(w0[i]);
    else if (i < 2*n) o1[i-n]     = f2bf(w1[i-n]);
    else if (i < 3*n) o2[i-2*n]   = f2bf(w2[i-2*n]);
    else if (i < 4*n) o3[i-3*n]   = f2bf(w3[i-3*n]);
}

// ---- pack mask into per-(t, keycol) 24-bit words ----
__global__ void maskb_kernel(const int* __restrict__ mask, unsigned int* __restrict__ maskb){
    int i = blockIdx.x*blockDim.x + threadIdx.x;   // over CT*CTL
    if (i >= CT*CTL) return;
    int t = i / CTL, m = i - t*CTL;
    unsigned w = 0;
    for (int n = 0; n < 24; ++n)
        if (mask[(size_t)(t*24 + n)*CTL + m] != 0) w |= (1u << n);
    maskb[i] = w;
}

// ---- projection GEMM: Y = A[rows x 512] @ W(bf16)[512 x 512]^T ----
// AFMT 0: A is fp32 (reg-staged + cvt to LDS); AFMT 1: A is bf16 (GL16)
// MODE 0: out bf16 [((bb*H+h)*posPer + pos)*64 + dh]   (qp, kp)
// MODE 1: out bf16 [((bb*H+h)*64 + dh)*posPer + pos]   (vpT)
// MODE 2: out fp32 [row*512 + col]                     (final out)
template<int MODE, int AFMT>
__global__ __launch_bounds__(256) void proj_gemm(
    const void* __restrict__ Ap, const unsigned short* __restrict__ W,
    void* __restrict__ outv, int posPer, float scale)
{
    __shared__ union {
        struct { unsigned short As[128*32]; unsigned short Bs[128*32]; } s;
        float epi[32][129];
    } sm;

    int nwg = gridDim.x*gridDim.y;
    int id  = blockIdx.y*gridDim.x + blockIdx.x;
    int q8 = nwg >> 3, r8 = nwg & 7;
    int xcd = id & 7, rk = id >> 3;
    int swz = (xcd < r8 ? xcd*(q8+1) : r8*(q8+1) + (xcd-r8)*q8) + rk;
    int ctile = swz & 3;
    int bt    = swz >> 2;

    int lane = threadIdx.x & 63, wave = threadIdx.x >> 6;
    int wr = wave >> 1, wc = wave & 1;
    int sr = threadIdx.x >> 2, sc = (threadIdx.x & 3)*8;

    const unsigned short* gb = W + (size_t)(ctile*128 + sr)*CD + sc;
    const float*          gaf = (const float*)Ap + (size_t)(bt*128 + sr)*CD + sc;
    const unsigned short* gah = (const unsigned short*)Ap + (size_t)(bt*128 + sr)*CD + sc;
    unsigned short* lA = sm.s.As + wave*512;
    unsigned short* lB = sm.s.Bs + wave*512;

    f32x4 acc[4][4] = {};

    for (int k0 = 0; k0 < CD; k0 += 32) {
        GL16(gb + k0,         lB);
        GL16(gb + 64*CD + k0, lB + 2048);
        if (AFMT == 1) {
            GL16(gah + k0,         lA);
            GL16(gah + 64*CD + k0, lA + 2048);
        } else {
            bf16x8 a0 = cvt8(gaf + k0);
            bf16x8 a1 = cvt8(gaf + 64*CD + k0);
            *(bf16x8*)&sm.s.As[threadIdx.x*8]        = a0;
            *(bf16x8*)&sm.s.As[2048 + threadIdx.x*8] = a1;
        }
        __syncthreads();
        bf16x8 af[4], bf[4];
        #pragma unroll
        for (int mf = 0; mf < 4; ++mf)
            af[mf] = *(const bf16x8*)&sm.s.As[(wr*64 + mf*16 + (lane&15))*32 + (lane>>4)*8];
        #pragma unroll
        for (int nf = 0; nf < 4; ++nf)
            bf[nf] = *(const bf16x8*)&sm.s.Bs[(wc*64 + nf*16 + (lane&15))*32 + (lane>>4)*8];
        #pragma unroll
        for (int mf = 0; mf < 4; ++mf)
            #pragma unroll
            for (int nf = 0; nf < 4; ++nf)
                acc[mf][nf] = MFMA16(af[mf], bf[nf], acc[mf][nf]);
        __syncthreads();
    }

    unsigned short* outu = (unsigned short*)outv;
    float* outf = (float*)outv;
    for (int p = 0; p < 4; ++p) {
        if (wr == (p >> 1)) {
            #pragma unroll
            for (int mh = 0; mh < 2; ++mh) {
                int mf = (p&1)*2 + mh;
                #pragma unroll
                for (int nf = 0; nf < 4; ++nf)
                    #pragma unroll
                    for (int r = 0; r < 4; ++r)
                        sm.epi[mh*16 + 4*(lane>>4) + r][wc*64 + nf*16 + (lane&15)] = acc[mf][nf][r]*scale;
            }
        }
        __syncthreads();
        if (MODE == 1) {
            #pragma unroll
            for (int i = 0; i < 16; ++i) {
                int c2 = i*8 + wave*2 + (lane>>5);
                int gr = bt*128 + p*32 + (lane & 31);
                int bb = gr / posPer, pos = gr - bb*posPer;
                int hh = ctile*2 + (c2>>6), dh = c2 & 63;
                outu[((size_t)(bb*CH + hh)*64 + dh)*posPer + pos] = f2bf(sm.epi[lane&31][c2]);
            }
        } else {
            #pragma unroll
            for (int i = 0; i < 16; ++i) {
                int task = i*4 + wave;
                int lr = task >> 1, ch = task & 1;
                float val = sm.epi[lr][ch*64 + lane];
                int gr = bt*128 + p*32 + lr;
                if (MODE == 2) {
                    outf[(size_t)gr*CD + ctile*128 + ch*64 + lane] = val;
                } else {
                    int bb = gr / posPer, pos = gr - bb*posPer;
                    int hh = ctile*2 + ch;
                    outu[((size_t)(bb*CH + hh)*posPer + pos)*64 + lane] = f2bf(val);
                }
            }
        }
        __syncthreads();
    }
}

// ---- scores pass A: per-(b,h,t,keycol) partial max / sumexp over 24 query rows ----
__global__ __launch_bounds__(256) void scores_a_kernel(
    const unsigned short* __restrict__ qp, const unsigned short* __restrict__ kp,
    const unsigned int* __restrict__ maskb,
    float* __restrict__ pmax, float* __restrict__ psum)
{
    __shared__ float S[CTN][65];
    int mt = blockIdx.x;
    int h = blockIdx.y, b = blockIdx.z;
    int lane = threadIdx.x & 63, wave = threadIdx.x >> 6;
    const unsigned short* qbase = qp + (size_t)(b*CH + h)*CTN*64;
    const unsigned short* kbase = kp + (size_t)(b*CH + h)*CTL*64;
    int koff = 8*(lane>>4);
    f32x4 acc[3][4] = {};
    for (int k0 = 0; k0 < 64; k0 += 32) {
        bf16x8 bfr[4];
        #pragma unroll
        for (int cf = 0; cf < 4; ++cf)
            bfr[cf] = ldbf8(kbase + (size_t)(mt*64 + cf*16 + (lane&15))*64 + k0 + koff);
        #pragma unroll
        for (int i = 0; i < 3; ++i) {
            int rt = wave + 4*i;
            if (rt < 9) {
                bf16x8 a = ldbf8(qbase + (size_t)(rt*16 + (lane&15))*64 + k0 + koff);
                #pragma unroll
                for (int cf = 0; cf < 4; ++cf)
                    acc[i][cf] = MFMA16(a, bfr[cf], acc[i][cf]);
            }
        }
    }
    #pragma unroll
    for (int i = 0; i < 3; ++i) {
        int rt = wave + 4*i;
        if (rt < 9) {
            #pragma unroll
            for (int cf = 0; cf < 4; ++cf)
                #pragma unroll
                for (int r = 0; r < 4; ++r)
                    S[rt*16 + 4*(lane>>4) + r][cf*16 + (lane&15)] = acc[i][cf][r];
        }
    }
    __syncthreads();
    int mg0 = mt*64;
    for (int task = threadIdx.x; task < CT*64; task += 256) {
        int t = task >> 6, ml = task & 63;
        int mg = mg0 + ml;
        unsigned w = maskb[(size_t)t*CTL + mg];
        float mx = -INFINITY;
        float sv[24];
        #pragma unroll
        for (int i = 0; i < 24; ++i) {
            float s = ((w >> i) & 1u) ? -INFINITY : S[t*24 + i][ml];
            sv[i] = s;
            mx = fmaxf(mx, s);
        }
        float sum = 0.f;
        if (mx > -INFINITY) {
            #pragma unroll
            for (int i = 0; i < 24; ++i)
                if (sv[i] > -INFINITY) sum += __expf(sv[i] - mx);
        }
        size_t idx = ((size_t)(b*CH + h)*CT + t)*CTL + mg;
        pmax[idx] = mx; psum[idx] = sum;
    }
}

// ---- combine partial softmax stats across heads ----
__global__ void combine_kernel(const float* __restrict__ pmax, const float* __restrict__ psum,
                               float* __restrict__ gmax, float* __restrict__ gsum){
    size_t i = (size_t)blockIdx.x*blockDim.x + threadIdx.x;
    if (i >= (size_t)CB*CT*CTL) return;
    int m = (int)(i % CTL);
    size_t bt = i / CTL;
    int t = (int)(bt % CT), b = (int)(bt / CT);
    float pm[CH], ps[CH];
    float mx = -INFINITY;
    #pragma unroll
    for (int h = 0; h < CH; ++h) {
        size_t idx = ((size_t)(b*CH + h)*CT + t)*CTL + m;
        pm[h] = pmax[idx]; ps[h] = psum[idx];
        mx = fmaxf(mx, pm[h]);
    }
    float s = 0.f;
    if (mx > -INFINITY) {
        #pragma unroll
        for (int h = 0; h < CH; ++h)
            if (pm[h] > -INFINITY) s += ps[h]*__expf(pm[h] - mx);
    }
    gmax[i] = mx; gsum[i] = s;
}

// ---- fused pass B + PV: recompute QK^T, a=exp(S-g)/gs, write avis,
//      bf16 a-tile -> LDS -> PV MFMA; per-ms partials for PV and rowsum ----
__global__ __launch_bounds__(256) void fused_bpv(
    const unsigned short* __restrict__ qp, const unsigned short* __restrict__ kp,
    const unsigned short* __restrict__ vpT,
    const unsigned int* __restrict__ maskb,
    const float* __restrict__ gmax, const float* __restrict__ gsum,
    float* __restrict__ avis, float* __restrict__ pvpart, float* __restrict__ rowpart)
{
    __shared__ struct {
        unsigned short abf[CTN][68];   // 19584 B (pad 68 -> conflict-free b128 reads)
        float gs[CT][64];
        float gi[CT][64];
        unsigned int mb[CT][64];
    } sm;                               // 24192 B

    int ms = blockIdx.x;               // 8 slices of 768 keys
    int h = blockIdx.y, b = blockIdx.z;
    int bh = b*CH + h;
    int tid = threadIdx.x;
    int lane = tid & 63, wave = tid >> 6;
    int qq = lane & 15, g = lane >> 4;
    int koff = 8*g;
    int r0  = (wave == 0) ? 0 : (wave*2 + 1);   // row-tiles {0..2},{3,4},{5,6},{7,8}
    int nrt = (wave == 0) ? 3 : 2;

    const unsigned short* qbase = qp + (size_t)bh*CTN*64;
    const unsigned short* kbase = kp + (size_t)bh*CTL*64;
    const unsigned short* vb    = vpT + (size_t)bh*64*CTL;

    // Q fragments are invariant across key tiles: preload
    bf16x8 qf[3][2];
    #pragma unroll
    for (int i = 0; i < 3; ++i)
        if (i < nrt)
            #pragma unroll
            for (int x = 0; x < 2; ++x)
                qf[i][x] = ldbf8(qbase + (size_t)((r0+i)*16 + qq)*64 + x*32 + koff);

    f32x4 pv[3][4] = {};
    float rs[3][4] = {};

    for (int mt = 0; mt < 12; ++mt) {
        int mg0 = ms*768 + mt*64;
        // stage per-tile stats (writes safe: previous softmax readers fenced by prev barrier2)
        for (int e = tid; e < CT*64; e += 256) {
            int t = e >> 6, c = e & 63;
            size_t gix = ((size_t)b*CT + t)*CTL + mg0 + c;
            float gm = gmax[gix], gv = gsum[gix];
            sm.gs[t][c] = gm;
            sm.gi[t][c] = (gv > 0.f) ? 1.f/gv : 0.f;
            sm.mb[t][c] = maskb[(size_t)t*CTL + mg0 + c];
        }
        // K fragments for this tile (shared across row-tiles)
        bf16x8 kf[2][4];
        #pragma unroll
        for (int x = 0; x < 2; ++x)
            #pragma unroll
            for (int cf = 0; cf < 4; ++cf)
                kf[x][cf] = ldbf8(kbase + (size_t)(mg0 + cf*16 + qq)*64 + x*32 + koff);
        __syncthreads();   // barrier1: stage visible
        // per row-tile: QK^T then immediate softmax (low register pressure)
        #pragma unroll
        for (int i = 0; i < 3; ++i) {
            if (i < nrt) {
                f32x4 sacc[4] = {};
                #pragma unroll
                for (int x = 0; x < 2; ++x)
                    #pragma unroll
                    for (int cf = 0; cf < 4; ++cf)
                        sacc[cf] = MFMA16(qf[i][x], kf[x][cf], sacc[cf]);
                #pragma unroll
                for (int r = 0; r < 4; ++r) {
                    int row = (r0+i)*16 + 4*g + r;
                    int t = row / 24;
                    int rb = row - t*24;
                    float rsum = 0.f;
                    #pragma unroll
                    for (int cf = 0; cf < 4; ++cf) {
                        int col = cf*16 + qq;
                        float a = 0.f;
                        if (!((sm.mb[t][col] >> rb) & 1u))
                            a = __expf(sacc[cf][r] - sm.gs[t][col]) * sm.gi[t][col];
                        avis[((size_t)bh*CTN + row)*CTL + mg0 + col] = a;
                        sm.abf[row][col] = f2bf(a);
                        rsum += a;
                    }
                    rs[i][r] += rsum;
                }
            }
        }
        __syncthreads();   // barrier2: abf complete
        // PV accumulate from LDS bf16 tile
        #pragma unroll
        for (int x = 0; x < 2; ++x) {
            bf16x8 bv[4];
            #pragma unroll
            for (int cf = 0; cf < 4; ++cf)
                bv[cf] = ldbf8(vb + (size_t)(cf*16 + qq)*CTL + mg0 + x*32 + koff);
            #pragma unroll
            for (int i = 0; i < 3; ++i) {
                if (i < nrt) {
                    bf16x8 af = *(const bf16x8*)&sm.abf[(r0+i)*16 + qq][x*32 + koff];
                    #pragma unroll
                    for (int cf = 0; cf < 4; ++cf)
                        pv[i][cf] = MFMA16(af, bv[cf], pv[i][cf]);
                }
            }
        }
    }

    // rowsum: reduce over the 16 lanes (qq) sharing each row
    #pragma unroll
    for (int i = 0; i < 3; ++i)
        if (i < nrt)
            #pragma unroll
            for (int r = 0; r < 4; ++r) {
                float s = rs[i][r];
                s += __shfl_xor(s, 1); s += __shfl_xor(s, 2);
                s += __shfl_xor(s, 4); s += __shfl_xor(s, 8);
                if (qq == 0)
                    rowpart[(size_t)ms*(CB*CH*CTN) + (size_t)bh*CTN + (r0+i)*16 + 4*g + r] = s;
            }
    // PV partial write
    float* pb = pvpart + (size_t)(ms*64 + bh)*CTN*64;
    #pragma unroll
    for (int i = 0; i < 3; ++i)
        if (i < nrt)
            #pragma unroll
            for (int cf = 0; cf < 4; ++cf)
                #pragma unroll
                for (int r = 0; r < 4; ++r)
                    pb[((r0+i)*16 + 4*g + r)*64 + cf*16 + qq] = pv[i][cf][r];
}

// ---- reduce rowsum partials over ms ----
__global__ void rowsum_kernel(const float* __restrict__ rowpart, float* __restrict__ rowsum){
    int i = blockIdx.x*blockDim.x + threadIdx.x;
    if (i >= CB*CH*CTN) return;
    float s = 0.f;
    #pragma unroll
    for (int ms = 0; ms < 8; ++ms) s += rowpart[(size_t)ms*(CB*CH*CTN) + i];
    rowsum[i] = s;
}

// ---- reduce PV partials, renormalize, write oh bf16 ----
__global__ void pv_reduce_kernel(const float* __restrict__ pvpart, const float* __restrict__ rowsum,
                                 unsigned short* __restrict__ oh){
    int idx = blockIdx.x*blockDim.x + threadIdx.x;
    if (idx >= CB*CH*CTN*64) return;
    float s = 0.f;
    #pragma unroll
    for (int ms = 0; ms < 8; ++ms)
        s += pvpart[(size_t)ms*(CB*CH*CTN*64) + idx];
    int col = idx & 63;
    int rowbh = idx >> 6;
    int row = rowbh % CTN, bh = rowbh / CTN;
    float inv = 1.f / (rowsum[rowbh] + CEPS);
    int b = bh >> 3, h = bh & 7;
    oh[((size_t)b*CTN + row)*CD + h*64 + col] = f2bf(s*inv);
}

extern "C" void kernel_launch(void* const* d_in, const int* in_sizes, int n_in,
                              void* d_out, int out_size, void* d_ws, size_t ws_size,
                              hipStream_t stream)
{
    const float* q    = (const float*)d_in[0];
    const float* k    = (const float*)d_in[1];
    const float* v    = (const float*)d_in[2];
    const int*   mask = (const int*)  d_in[3];
    const float* Wq   = (const float*)d_in[4];
    const float* Wk   = (const float*)d_in[5];
    const float* Wv   = (const float*)d_in[6];
    const float* Wo   = (const float*)d_in[7];

    float* out0 = (float*)d_out;
    float* avis = out0 + (size_t)CB*CTN*CD;

    char* p = (char*)d_ws;
    auto alloc = [&](size_t bytes) -> char* {
        char* r = p; p += (bytes + 255) & ~(size_t)255; return r;
    };
    unsigned short* Wq_bf = (unsigned short*)alloc((size_t)CD*CD*2);
    unsigned short* Wk_bf = (unsigned short*)alloc((size_t)CD*CD*2);
    unsigned short* Wv_bf = (unsigned short*)alloc((size_t)CD*CD*2);
    unsigned short* Wo_bf = (unsigned short*)alloc((size_t)CD*CD*2);
    unsigned short* qp    = (unsigned short*)alloc((size_t)CB*CH*CTN*64*2);
    unsigned short* kp    = (unsigned short*)alloc((size_t)CB*CH*CTL*64*2);
    unsigned short* vpT   = (unsigned short*)alloc((size_t)CB*CH*64*CTL*2);
    // S region: phase A pmax|psum (9.44+9.44 MB); phase B pvpart (18.87 MB) aliases both
    char* S = alloc((size_t)CB*CH*CT*CTL*4*2);
    float* pmax   = (float*)S;
    float* psum   = (float*)(S + (size_t)CB*CH*CT*CTL*4);
    float* pvpart = (float*)S;
    float* gmax   = (float*)alloc((size_t)CB*CT*CTL*4);
    float* gsum   = (float*)alloc((size_t)CB*CT*CTL*4);
    unsigned int* maskb = (unsigned int*)alloc((size_t)CT*CTL*4);
    float* rowpart = (float*)alloc((size_t)8*CB*CH*CTN*4);
    float* rowsum  = (float*)alloc((size_t)CB*CH*CTN*4);
    unsigned short* oh = (unsigned short*)alloc((size_t)CB*CTN*CD*2);

    // 1. weights -> bf16; mask -> bitwords
    cvt_w_kernel<<<(4*CD*CD + 255)/256, 256, 0, stream>>>(Wq, Wk, Wv, Wo,
                                                          Wq_bf, Wk_bf, Wv_bf, Wo_bf);
    maskb_kernel<<<(CT*CTL + 255)/256, 256, 0, stream>>>(mask, maskb);
    // 2. projections (fp32 A reg-staged, W via global_load_lds)
    proj_gemm<0,0><<<dim3(4, CB*CTN/128), 256, 0, stream>>>(q, Wq_bf, qp, CTN, 0.125f);
    proj_gemm<0,0><<<dim3(4, CB*CTL/128), 256, 0, stream>>>(k, Wk_bf, kp, CTL, 1.0f);
    proj_gemm<1,0><<<dim3(4, CB*CTL/128), 256, 0, stream>>>(v, Wv_bf, vpT, CTL, 1.0f);
    // 3. scores pass A: partial softmax stats
    scores_a_kernel<<<dim3(CTL/64, CH, CB), 256, 0, stream>>>(qp, kp, maskb, pmax, psum);
    // 4. combine across heads
    combine_kernel<<<((CB*CT*CTL) + 255)/256, 256, 0, stream>>>(pmax, psum, gmax, gsum);
    // 5. fused pass B + PV (pvpart aliases dead pmax/psum)
    fused_bpv<<<dim3(8, CH, CB), 256, 0, stream>>>(qp, kp, vpT, maskb, gmax, gsum,
                                                   avis, pvpart, rowpart);
    // 6. reduce rowsums and PV partials
    rowsum_kernel<<<((CB*CH*CTN) + 255)/256, 256, 0, stream>>>(rowpart, rowsum);
    pv_reduce_kernel<<<((CB*CH*CTN*64) + 255)/256, 256, 0, stream>>>(pvpart, rowsum, oh);
    // 7. output projection
    proj_gemm<2,1><<<dim3(4, CB*CTN/128), 256, 0, stream>>>(oh, Wo_bf, out0, CD, 1.0f);
}

// Round 4
// 962.415 us; speedup vs baseline: 1.2011x; 1.1746x over previous
//
#include <hip/hip_runtime.h>
#include <hip/hip_bf16.h>
#include <math.h>

// ---- problem constants ----
#define CB 8
#define CT 6
#define CN 24
#define CL 1024
#define CD 512
#define CH 8
#define CDH 64
#define CTN 144     // T*N
#define CTL 6144    // T*L
#define CEPS 1e-5f

typedef __bf16 bf16x8 __attribute__((ext_vector_type(8)));
typedef float  f32x4  __attribute__((ext_vector_type(4)));

#define MFMA16(a,b,c) __builtin_amdgcn_mfma_f32_16x16x32_bf16(a,b,c,0,0,0)

union BF8 { unsigned short s[8]; bf16x8 v; };

static __device__ __forceinline__ unsigned short f2bf(float x){
    union { float f; unsigned u; } c; c.f = x;
    return (unsigned short)((c.u + 0x7FFFu + ((c.u >> 16) & 1u)) >> 16);
}

static __device__ __forceinline__ bf16x8 cvt8(const float* __restrict__ p){
    const f32x4* q = (const f32x4*)p;
    f32x4 v0 = q[0], v1 = q[1];
    BF8 r;
    r.s[0]=f2bf(v0[0]); r.s[1]=f2bf(v0[1]); r.s[2]=f2bf(v0[2]); r.s[3]=f2bf(v0[3]);
    r.s[4]=f2bf(v1[0]); r.s[5]=f2bf(v1[1]); r.s[6]=f2bf(v1[2]); r.s[7]=f2bf(v1[3]);
    return r.v;
}

static __device__ __forceinline__ bf16x8 ldbf8(const unsigned short* __restrict__ p){
    return *(const bf16x8*)p;
}

#define GL16(gp, lp) __builtin_amdgcn_global_load_lds((const unsigned int*)(gp), (unsigned int*)(lp), 16, 0, 0)

// ---- convert weights to bf16 ----
__global__ void cvt_w_kernel(const float* __restrict__ w0, const float* __restrict__ w1,
                             const float* __restrict__ w2, const float* __restrict__ w3,
                             unsigned short* __restrict__ o0, unsigned short* __restrict__ o1,
                             unsigned short* __restrict__ o2, unsigned short* __restrict__ o3){
    int i = blockIdx.x*blockDim.x + threadIdx.x;
    const int n = CD*CD;
    if      (i < n)   o0[i]       = f2bf(w0[i]);
    else if (i < 2*n) o1[i-n]     = f2bf(w1[i-n]);
    else if (i < 3*n) o2[i-2*n]   = f2bf(w2[i-2*n]);
    else if (i < 4*n) o3[i-3*n]   = f2bf(w3[i-3*n]);
}

// ---- pack mask into per-(t, keycol) 24-bit words ----
__global__ void maskb_kernel(const int* __restrict__ mask, unsigned int* __restrict__ maskb){
    int i = blockIdx.x*blockDim.x + threadIdx.x;   // over CT*CTL
    if (i >= CT*CTL) return;
    int t = i / CTL, m = i - t*CTL;
    unsigned w = 0;
    for (int n = 0; n < 24; ++n)
        if (mask[(size_t)(t*24 + n)*CTL + m] != 0) w |= (1u << n);
    maskb[i] = w;
}

// ---- convert fp32 -> bf16, 8 elems/thread ----
__global__ void cvt_x_kernel(const float* __restrict__ src, unsigned short* __restrict__ dst, int n8){
    int i = blockIdx.x*blockDim.x + threadIdx.x;
    if (i >= n8) return;
    *(bf16x8*)(dst + (size_t)i*8) = cvt8(src + (size_t)i*8);
}

// ---- m97-style GEMM: Y = A(bf16)[rows x 512] @ W(bf16)[512 x 512]^T ----
// k-slot XOR swizzle: LDS row r (64B per k0-step) holds k-group g at slot
// g ^ ((r>>1)&3); GL16 source is pre-swizzled, LDS dest stays linear (m173).
// MODE 0: out bf16 [((bb*H+h)*posPer + pos)*64 + dh]   (qp, kp)
// MODE 1: out bf16 [((bb*H+h)*64 + dh)*posPer + pos]   (vpT)
// MODE 2: out fp32 [row*512 + col]                     (final out)
template<int MODE>
__global__ __launch_bounds__(256) void gemm_m97(
    const unsigned short* __restrict__ A, const unsigned short* __restrict__ W,
    void* __restrict__ outv, int posPer, int rowoff, float scale)
{
    __shared__ union {
        struct { unsigned short As[128*32]; unsigned short Bs[128*32]; } s;
        float epi[32][129];
    } sm;

    // bijective XCD swizzle
    int nwg = gridDim.x*gridDim.y;
    int id  = blockIdx.y*gridDim.x + blockIdx.x;
    int q8 = nwg >> 3, r8 = nwg & 7;
    int xcd = id & 7, rk = id >> 3;
    int swz = (xcd < r8 ? xcd*(q8+1) : r8*(q8+1) + (xcd-r8)*q8) + rk;
    int ctile = swz & 3;
    int bt    = swz >> 2;

    int lane = threadIdx.x & 63, wave = threadIdx.x >> 6;
    int wr = wave >> 1, wc = wave & 1;
    int qq = lane & 15, g = lane >> 4;

    int sr = threadIdx.x >> 2;
    int sc = (((threadIdx.x & 3) ^ ((sr >> 1) & 3)) * 8);   // pre-swizzled k-slot
    const unsigned short* ga = A + (size_t)(bt*128 + sr)*CD + sc;
    const unsigned short* gb = W + (size_t)(ctile*128 + sr)*CD + sc;
    unsigned short* lA = sm.s.As + wave*512;
    unsigned short* lB = sm.s.Bs + wave*512;

    f32x4 acc[4][4] = {};
    int slotA = ((g ^ ((qq >> 1) & 3)) * 8);

    for (int k0 = 0; k0 < CD; k0 += 32) {
        GL16(ga + k0,          lA);
        GL16(ga + 64*CD + k0,  lA + 2048);
        GL16(gb + k0,          lB);
        GL16(gb + 64*CD + k0,  lB + 2048);
        __syncthreads();
        bf16x8 af[4], bf[4];
        #pragma unroll
        for (int mf = 0; mf < 4; ++mf)
            af[mf] = *(const bf16x8*)&sm.s.As[(wr*64 + mf*16 + qq)*32 + slotA];
        #pragma unroll
        for (int nf = 0; nf < 4; ++nf)
            bf[nf] = *(const bf16x8*)&sm.s.Bs[(wc*64 + nf*16 + qq)*32 + slotA];
        #pragma unroll
        for (int mf = 0; mf < 4; ++mf)
            #pragma unroll
            for (int nf = 0; nf < 4; ++nf)
                acc[mf][nf] = MFMA16(af[mf], bf[nf], acc[mf][nf]);
        __syncthreads();
    }

    // epilogue: 4 passes of 32 rows through LDS (fp32, padded 129 -> conflict-free)
    unsigned short* outu = (unsigned short*)outv;
    float* outf = (float*)outv;
    for (int p = 0; p < 4; ++p) {
        if (wr == (p >> 1)) {
            #pragma unroll
            for (int mh = 0; mh < 2; ++mh) {
                int mf = (p&1)*2 + mh;
                #pragma unroll
                for (int nf = 0; nf < 4; ++nf)
                    #pragma unroll
                    for (int r = 0; r < 4; ++r)
                        sm.epi[mh*16 + 4*(lane>>4) + r][wc*64 + nf*16 + (lane&15)] = acc[mf][nf][r]*scale;
            }
        }
        __syncthreads();
        if (MODE == 1) {
            #pragma unroll
            for (int i = 0; i < 16; ++i) {
                int c2 = i*8 + wave*2 + (lane>>5);
                int gr = rowoff + bt*128 + p*32 + (lane & 31);
                int bb = gr / posPer, pos = gr - bb*posPer;
                int hh = ctile*2 + (c2>>6), dh = c2 & 63;
                outu[((size_t)(bb*CH + hh)*64 + dh)*posPer + pos] = f2bf(sm.epi[lane&31][c2]);
            }
        } else {
            #pragma unroll
            for (int i = 0; i < 16; ++i) {
                int task = i*4 + wave;     // 0..63: (lr, ch)
                int lr = task >> 1, ch = task & 1;
                float val = sm.epi[lr][ch*64 + lane];
                int gr = rowoff + bt*128 + p*32 + lr;
                if (MODE == 2) {
                    outf[(size_t)gr*CD + ctile*128 + ch*64 + lane] = val;
                } else {
                    int bb = gr / posPer, pos = gr - bb*posPer;
                    int hh = ctile*2 + ch;
                    outu[((size_t)(bb*CH + hh)*posPer + pos)*64 + lane] = f2bf(val);
                }
            }
        }
        __syncthreads();
    }
}

// ---- scores pass A: per-(b,h,t,keycol) partial max / sumexp over 24 query rows ----
__global__ __launch_bounds__(256) void scores_a_kernel(
    const unsigned short* __restrict__ qp, const unsigned short* __restrict__ kp,
    const unsigned int* __restrict__ maskb,
    float* __restrict__ pmax, float* __restrict__ psum)
{
    __shared__ float S[CTN][65];
    int mt = blockIdx.x;
    int h = blockIdx.y, b = blockIdx.z;
    int lane = threadIdx.x & 63, wave = threadIdx.x >> 6;
    const unsigned short* qbase = qp + (size_t)(b*CH + h)*CTN*64;
    const unsigned short* kbase = kp + (size_t)(b*CH + h)*CTL*64;
    int koff = 8*(lane>>4);
    f32x4 acc[3][4] = {};
    for (int k0 = 0; k0 < 64; k0 += 32) {
        bf16x8 bfr[4];
        #pragma unroll
        for (int cf = 0; cf < 4; ++cf)
            bfr[cf] = ldbf8(kbase + (size_t)(mt*64 + cf*16 + (lane&15))*64 + k0 + koff);
        #pragma unroll
        for (int i = 0; i < 3; ++i) {
            int rt = wave + 4*i;
            if (rt < 9) {
                bf16x8 a = ldbf8(qbase + (size_t)(rt*16 + (lane&15))*64 + k0 + koff);
                #pragma unroll
                for (int cf = 0; cf < 4; ++cf)
                    acc[i][cf] = MFMA16(a, bfr[cf], acc[i][cf]);
            }
        }
    }
    #pragma unroll
    for (int i = 0; i < 3; ++i) {
        int rt = wave + 4*i;
        if (rt < 9) {
            #pragma unroll
            for (int cf = 0; cf < 4; ++cf)
                #pragma unroll
                for (int r = 0; r < 4; ++r)
                    S[rt*16 + 4*(lane>>4) + r][cf*16 + (lane&15)] = acc[i][cf][r];
        }
    }
    __syncthreads();
    int mg0 = mt*64;
    for (int task = threadIdx.x; task < CT*64; task += 256) {
        int t = task >> 6, ml = task & 63;
        int mg = mg0 + ml;
        unsigned w = maskb[(size_t)t*CTL + mg];
        float mx = -INFINITY;
        float sv[24];
        #pragma unroll
        for (int i = 0; i < 24; ++i) {
            float s = ((w >> i) & 1u) ? -INFINITY : S[t*24 + i][ml];
            sv[i] = s;
            mx = fmaxf(mx, s);
        }
        float sum = 0.f;
        if (mx > -INFINITY) {
            #pragma unroll
            for (int i = 0; i < 24; ++i)
                if (sv[i] > -INFINITY) sum += __expf(sv[i] - mx);
        }
        size_t idx = ((size_t)(b*CH + h)*CT + t)*CTL + mg;
        pmax[idx] = mx; psum[idx] = sum;
    }
}

// ---- combine partial softmax stats across heads ----
__global__ void combine_kernel(const float* __restrict__ pmax, const float* __restrict__ psum,
                               float* __restrict__ gmax, float* __restrict__ gsum){
    size_t i = (size_t)blockIdx.x*blockDim.x + threadIdx.x;
    if (i >= (size_t)CB*CT*CTL) return;
    int m = (int)(i % CTL);
    size_t bt = i / CTL;
    int t = (int)(bt % CT), b = (int)(bt / CT);
    float pm[CH], ps[CH];
    float mx = -INFINITY;
    #pragma unroll
    for (int h = 0; h < CH; ++h) {
        size_t idx = ((size_t)(b*CH + h)*CT + t)*CTL + m;
        pm[h] = pmax[idx]; ps[h] = psum[idx];
        mx = fmaxf(mx, pm[h]);
    }
    float s = 0.f;
    if (mx > -INFINITY) {
        #pragma unroll
        for (int h = 0; h < CH; ++h)
            if (pm[h] > -INFINITY) s += ps[h]*__expf(pm[h] - mx);
    }
    gmax[i] = mx; gsum[i] = s;
}

// ---- fused pass B + PV ----
__global__ __launch_bounds__(256) void fused_bpv(
    const unsigned short* __restrict__ qp, const unsigned short* __restrict__ kp,
    const unsigned short* __restrict__ vpT,
    const unsigned int* __restrict__ maskb,
    const float* __restrict__ gmax, const float* __restrict__ gsum,
    float* __restrict__ avis, float* __restrict__ pvpart, float* __restrict__ rowpart)
{
    __shared__ struct {
        unsigned short abf[CTN][68];
        float gs[CT][64];
        float gi[CT][64];
        unsigned int mb[CT][64];
    } sm;

    int ms = blockIdx.x;               // 8 slices of 768 keys
    int h = blockIdx.y, b = blockIdx.z;
    int bh = b*CH + h;
    int tid = threadIdx.x;
    int lane = tid & 63, wave = tid >> 6;
    int qq = lane & 15, g = lane >> 4;
    int koff = 8*g;
    int r0  = (wave == 0) ? 0 : (wave*2 + 1);
    int nrt = (wave == 0) ? 3 : 2;

    const unsigned short* qbase = qp + (size_t)bh*CTN*64;
    const unsigned short* kbase = kp + (size_t)bh*CTL*64;
    const unsigned short* vb    = vpT + (size_t)bh*64*CTL;

    bf16x8 qf[3][2];
    #pragma unroll
    for (int i = 0; i < 3; ++i)
        if (i < nrt)
            #pragma unroll
            for (int x = 0; x < 2; ++x)
                qf[i][x] = ldbf8(qbase + (size_t)((r0+i)*16 + qq)*64 + x*32 + koff);

    f32x4 pv[3][4] = {};
    float rs[3][4] = {};

    for (int mt = 0; mt < 12; ++mt) {
        int mg0 = ms*768 + mt*64;
        for (int e = tid; e < CT*64; e += 256) {
            int t = e >> 6, c = e & 63;
            size_t gix = ((size_t)b*CT + t)*CTL + mg0 + c;
            float gm = gmax[gix], gv = gsum[gix];
            sm.gs[t][c] = gm;
            sm.gi[t][c] = (gv > 0.f) ? 1.f/gv : 0.f;
            sm.mb[t][c] = maskb[(size_t)t*CTL + mg0 + c];
        }
        bf16x8 kf[2][4];
        #pragma unroll
        for (int x = 0; x < 2; ++x)
            #pragma unroll
            for (int cf = 0; cf < 4; ++cf)
                kf[x][cf] = ldbf8(kbase + (size_t)(mg0 + cf*16 + qq)*64 + x*32 + koff);
        __syncthreads();
        #pragma unroll
        for (int i = 0; i < 3; ++i) {
            if (i < nrt) {
                f32x4 sacc[4] = {};
                #pragma unroll
                for (int x = 0; x < 2; ++x)
                    #pragma unroll
                    for (int cf = 0; cf < 4; ++cf)
                        sacc[cf] = MFMA16(qf[i][x], kf[x][cf], sacc[cf]);
                #pragma unroll
                for (int r = 0; r < 4; ++r) {
                    int row = (r0+i)*16 + 4*g + r;
                    int t = row / 24;
                    int rb = row - t*24;
                    float rsum = 0.f;
                    #pragma unroll
                    for (int cf = 0; cf < 4; ++cf) {
                        int col = cf*16 + qq;
                        float a = 0.f;
                        if (!((sm.mb[t][col] >> rb) & 1u))
                            a = __expf(sacc[cf][r] - sm.gs[t][col]) * sm.gi[t][col];
                        avis[((size_t)bh*CTN + row)*CTL + mg0 + col] = a;
                        sm.abf[row][col] = f2bf(a);
                        rsum += a;
                    }
                    rs[i][r] += rsum;
                }
            }
        }
        __syncthreads();
        #pragma unroll
        for (int x = 0; x < 2; ++x) {
            bf16x8 bv[4];
            #pragma unroll
            for (int cf = 0; cf < 4; ++cf)
                bv[cf] = ldbf8(vb + (size_t)(cf*16 + qq)*CTL + mg0 + x*32 + koff);
            #pragma unroll
            for (int i = 0; i < 3; ++i) {
                if (i < nrt) {
                    bf16x8 af = *(const bf16x8*)&sm.abf[(r0+i)*16 + qq][x*32 + koff];
                    #pragma unroll
                    for (int cf = 0; cf < 4; ++cf)
                        pv[i][cf] = MFMA16(af, bv[cf], pv[i][cf]);
                }
            }
        }
    }

    #pragma unroll
    for (int i = 0; i < 3; ++i)
        if (i < nrt)
            #pragma unroll
            for (int r = 0; r < 4; ++r) {
                float s = rs[i][r];
                s += __shfl_xor(s, 1); s += __shfl_xor(s, 2);
                s += __shfl_xor(s, 4); s += __shfl_xor(s, 8);
                if (qq == 0)
                    rowpart[(size_t)ms*(CB*CH*CTN) + (size_t)bh*CTN + (r0+i)*16 + 4*g + r] = s;
            }
    float* pb = pvpart + (size_t)(ms*64 + bh)*CTN*64;
    #pragma unroll
    for (int i = 0; i < 3; ++i)
        if (i < nrt)
            #pragma unroll
            for (int cf = 0; cf < 4; ++cf)
                #pragma unroll
                for (int r = 0; r < 4; ++r)
                    pb[((r0+i)*16 + 4*g + r)*64 + cf*16 + qq] = pv[i][cf][r];
}

// ---- reduce rowsum partials over ms ----
__global__ void rowsum_kernel(const float* __restrict__ rowpart, float* __restrict__ rowsum){
    int i = blockIdx.x*blockDim.x + threadIdx.x;
    if (i >= CB*CH*CTN) return;
    float s = 0.f;
    #pragma unroll
    for (int ms = 0; ms < 8; ++ms) s += rowpart[(size_t)ms*(CB*CH*CTN) + i];
    rowsum[i] = s;
}

// ---- reduce PV partials, renormalize, write oh bf16 ----
__global__ void pv_reduce_kernel(const float* __restrict__ pvpart, const float* __restrict__ rowsum,
                                 unsigned short* __restrict__ oh){
    int idx = blockIdx.x*blockDim.x + threadIdx.x;
    if (idx >= CB*CH*CTN*64) return;
    float s = 0.f;
    #pragma unroll
    for (int ms = 0; ms < 8; ++ms)
        s += pvpart[(size_t)ms*(CB*CH*CTN*64) + idx];
    int col = idx & 63;
    int rowbh = idx >> 6;
    int row = rowbh % CTN, bh = rowbh / CTN;
    float inv = 1.f / (rowsum[rowbh] + CEPS);
    int b = bh >> 3, h = bh & 7;
    oh[((size_t)b*CTN + row)*CD + h*64 + col] = f2bf(s*inv);
}

extern "C" void kernel_launch(void* const* d_in, const int* in_sizes, int n_in,
                              void* d_out, int out_size, void* d_ws, size_t ws_size,
                              hipStream_t stream)
{
    const float* q    = (const float*)d_in[0];
    const float* k    = (const float*)d_in[1];
    const float* v    = (const float*)d_in[2];
    const int*   mask = (const int*)  d_in[3];
    const float* Wq   = (const float*)d_in[4];
    const float* Wk   = (const float*)d_in[5];
    const float* Wv   = (const float*)d_in[6];
    const float* Wo   = (const float*)d_in[7];

    float* out0 = (float*)d_out;
    float* avis = out0 + (size_t)CB*CTN*CD;

    char* p = (char*)d_ws;
    auto alloc = [&](size_t bytes) -> char* {
        char* r = p; p += (bytes + 255) & ~(size_t)255; return r;
    };
    unsigned short* Wq_bf = (unsigned short*)alloc((size_t)CD*CD*2);
    unsigned short* Wk_bf = (unsigned short*)alloc((size_t)CD*CD*2);
    unsigned short* Wv_bf = (unsigned short*)alloc((size_t)CD*CD*2);
    unsigned short* Wo_bf = (unsigned short*)alloc((size_t)CD*CD*2);
    unsigned short* qp    = (unsigned short*)alloc((size_t)CB*CH*CTN*64*2);
    unsigned short* kp    = (unsigned short*)alloc((size_t)CB*CH*CTL*64*2);
    unsigned short* vpT   = (unsigned short*)alloc((size_t)CB*CH*64*CTL*2);
    // S region (18.87 MB), time-multiplexed:
    //   proj phase:  xbf chunk buffer (16.78 MB)
    //   scores A:    pmax (9.44) | psum (9.44)
    //   fused_bpv:   pvpart (18.87) aliases dead pmax/psum
    char* S = alloc((size_t)CB*CH*CT*CTL*4*2);
    unsigned short* xbf = (unsigned short*)S;
    float* pmax   = (float*)S;
    float* psum   = (float*)(S + (size_t)CB*CH*CT*CTL*4);
    float* pvpart = (float*)S;
    float* gmax   = (float*)alloc((size_t)CB*CT*CTL*4);
    float* gsum   = (float*)alloc((size_t)CB*CT*CTL*4);
    unsigned int* maskb = (unsigned int*)alloc((size_t)CT*CTL*4);
    float* rowpart = (float*)alloc((size_t)8*CB*CH*CTN*4);
    float* rowsum  = (float*)alloc((size_t)CB*CH*CTN*4);
    unsigned short* oh = (unsigned short*)alloc((size_t)CB*CTN*CD*2);

    // 1. weights -> bf16; mask -> bitwords
    cvt_w_kernel<<<(4*CD*CD + 255)/256, 256, 0, stream>>>(Wq, Wk, Wv, Wo,
                                                          Wq_bf, Wk_bf, Wv_bf, Wo_bf);
    maskb_kernel<<<(CT*CTL + 255)/256, 256, 0, stream>>>(mask, maskb);
    // 2. q projection
    cvt_x_kernel<<<(CB*CTN*CD/8 + 255)/256, 256, 0, stream>>>(q, xbf, CB*CTN*CD/8);
    gemm_m97<0><<<dim3(4, CB*CTN/128), 256, 0, stream>>>(xbf, Wq_bf, qp, CTN, 0, 0.125f);
    // 3. k projection, 3 chunks of 16384 rows (keeps per-XCD L2 footprint ~2 MB)
    for (int c = 0; c < 3; ++c) {
        cvt_x_kernel<<<(16384*CD/8 + 255)/256, 256, 0, stream>>>(k + (size_t)c*16384*CD, xbf, 16384*CD/8);
        gemm_m97<0><<<dim3(4, 128), 256, 0, stream>>>(xbf, Wk_bf, kp, CTL, c*16384, 1.0f);
    }
    // 4. v projection (transposed output), 3 chunks
    for (int c = 0; c < 3; ++c) {
        cvt_x_kernel<<<(16384*CD/8 + 255)/256, 256, 0, stream>>>(v + (size_t)c*16384*CD, xbf, 16384*CD/8);
        gemm_m97<1><<<dim3(4, 128), 256, 0, stream>>>(xbf, Wv_bf, vpT, CTL, c*16384, 1.0f);
    }
    // 5. scores pass A
    scores_a_kernel<<<dim3(CTL/64, CH, CB), 256, 0, stream>>>(qp, kp, maskb, pmax, psum);
    // 6. combine across heads
    combine_kernel<<<((CB*CT*CTL) + 255)/256, 256, 0, stream>>>(pmax, psum, gmax, gsum);
    // 7. fused pass B + PV
    fused_bpv<<<dim3(8, CH, CB), 256, 0, stream>>>(qp, kp, vpT, maskb, gmax, gsum,
                                                   avis, pvpart, rowpart);
    // 8. reduce rowsums and PV partials
    rowsum_kernel<<<((CB*CH*CTN) + 255)/256, 256, 0, stream>>>(rowpart, rowsum);
    pv_reduce_kernel<<<((CB*CH*CTN*64) + 255)/256, 256, 0, stream>>>(pvpart, rowsum, oh);
    // 9. output projection
    gemm_m97<2><<<dim3(4, CB*CTN/128), 256, 0, stream>>>(oh, Wo_bf, out0, CD, 0, 1.0f);
}

// Round 5
// 539.100 us; speedup vs baseline: 2.1443x; 1.7852x over previous
//
#include <hip/hip_runtime.h>
#include <hip/hip_bf16.h>
#include <math.h>

// ---- problem constants ----
#define CB 8
#define CT 6
#define CN 24
#define CL 1024
#define CD 512
#define CH 8
#define CDH 64
#define CTN 144     // T*N
#define CTL 6144    // T*L
#define CEPS 1e-5f

typedef __bf16 bf16x8 __attribute__((ext_vector_type(8)));
typedef float  f32x4  __attribute__((ext_vector_type(4)));

#define MFMA16(a,b,c) __builtin_amdgcn_mfma_f32_16x16x32_bf16(a,b,c,0,0,0)

union BF8 { unsigned short s[8]; bf16x8 v; };

static __device__ __forceinline__ unsigned short f2bf(float x){
    union { float f; unsigned u; } c; c.f = x;
    return (unsigned short)((c.u + 0x7FFFu + ((c.u >> 16) & 1u)) >> 16);
}

static __device__ __forceinline__ bf16x8 cvt8(const float* __restrict__ p){
    const f32x4* q = (const f32x4*)p;
    f32x4 v0 = q[0], v1 = q[1];
    BF8 r;
    r.s[0]=f2bf(v0[0]); r.s[1]=f2bf(v0[1]); r.s[2]=f2bf(v0[2]); r.s[3]=f2bf(v0[3]);
    r.s[4]=f2bf(v1[0]); r.s[5]=f2bf(v1[1]); r.s[6]=f2bf(v1[2]); r.s[7]=f2bf(v1[3]);
    return r.v;
}

static __device__ __forceinline__ bf16x8 ldbf8(const unsigned short* __restrict__ p){
    return *(const bf16x8*)p;
}

#define GL16(gp, lp) __builtin_amdgcn_global_load_lds((const unsigned int*)(gp), (unsigned int*)(lp), 16, 0, 0)

// ---- convert weights to bf16 ----
__global__ void cvt_w_kernel(const float* __restrict__ w0, const float* __restrict__ w1,
                             const float* __restrict__ w2, const float* __restrict__ w3,
                             unsigned short* __restrict__ o0, unsigned short* __restrict__ o1,
                             unsigned short* __restrict__ o2, unsigned short* __restrict__ o3){
    int i = blockIdx.x*blockDim.x + threadIdx.x;
    const int n = CD*CD;
    if      (i < n)   o0[i]       = f2bf(w0[i]);
    else if (i < 2*n) o1[i-n]     = f2bf(w1[i-n]);
    else if (i < 3*n) o2[i-2*n]   = f2bf(w2[i-2*n]);
    else if (i < 4*n) o3[i-3*n]   = f2bf(w3[i-3*n]);
}

// ---- pack mask into per-(t, keycol) 24-bit words ----
__global__ void maskb_kernel(const int* __restrict__ mask, unsigned int* __restrict__ maskb){
    int i = blockIdx.x*blockDim.x + threadIdx.x;   // over CT*CTL
    if (i >= CT*CTL) return;
    int t = i / CTL, m = i - t*CTL;
    unsigned w = 0;
    for (int n = 0; n < 24; ++n)
        if (mask[(size_t)(t*24 + n)*CTL + m] != 0) w |= (1u << n);
    maskb[i] = w;
}

// ---- convert fp32 -> bf16, 8 elems/thread ----
__global__ void cvt_x_kernel(const float* __restrict__ src, unsigned short* __restrict__ dst, int n8){
    int i = blockIdx.x*blockDim.x + threadIdx.x;
    if (i >= n8) return;
    *(bf16x8*)(dst + (size_t)i*8) = cvt8(src + (size_t)i*8);
}

// ---- 8-wave m97 GEMM: Y = A(bf16)[rows x 512] @ W(bf16)[512 x 512]^T ----
// 128x128 tile, 8 waves (2 row x 4 col), wave sub-tile 64x32, acc[4][2].
// k-slot XOR swizzle via pre-swizzled GL16 source (LDS dest linear).
// MODE 0: out bf16 [((bb*H+h)*posPer + pos)*64 + dh]   (qp, kp)
// MODE 1: out bf16 [((bb*H+h)*64 + dh)*posPer + pos]   (vpT)
// MODE 2: out fp32 [row*512 + col]                     (final out)
template<int MODE>
__global__ __launch_bounds__(512, 4) void gemm_m97(
    const unsigned short* __restrict__ A, const unsigned short* __restrict__ W,
    void* __restrict__ outv, int posPer, int rowoff, float scale)
{
    __shared__ union {
        struct { unsigned short As[128*32]; unsigned short Bs[128*32]; } s;
        float epi[32][129];
    } sm;

    // bijective XCD swizzle
    int nwg = gridDim.x*gridDim.y;
    int id  = blockIdx.y*gridDim.x + blockIdx.x;
    int q8 = nwg >> 3, r8 = nwg & 7;
    int xcd = id & 7, rk = id >> 3;
    int swz = (xcd < r8 ? xcd*(q8+1) : r8*(q8+1) + (xcd-r8)*q8) + rk;
    int ctile = swz & 3;
    int bt    = swz >> 2;

    int tid = threadIdx.x;
    int lane = tid & 63, wave = tid >> 6;
    int wr = wave >> 2, wc = wave & 3;
    int qq = lane & 15, g = lane >> 4;

    int sr = tid >> 2;
    int sc = (((tid & 3) ^ ((sr >> 1) & 3)) * 8);   // pre-swizzled k-slot
    const unsigned short* ga = A + (size_t)(bt*128 + sr)*CD + sc;
    const unsigned short* gb = W + (size_t)(ctile*128 + sr)*CD + sc;
    unsigned short* lA = sm.s.As + wave*512;
    unsigned short* lB = sm.s.Bs + wave*512;

    f32x4 acc[4][2] = {};
    int slotA = ((g ^ ((qq >> 1) & 3)) * 8);

    for (int k0 = 0; k0 < CD; k0 += 32) {
        GL16(ga + k0, lA);
        GL16(gb + k0, lB);
        __syncthreads();
        bf16x8 af[4], bf[2];
        #pragma unroll
        for (int mf = 0; mf < 4; ++mf)
            af[mf] = *(const bf16x8*)&sm.s.As[(wr*64 + mf*16 + qq)*32 + slotA];
        #pragma unroll
        for (int nf = 0; nf < 2; ++nf)
            bf[nf] = *(const bf16x8*)&sm.s.Bs[(wc*32 + nf*16 + qq)*32 + slotA];
        #pragma unroll
        for (int mf = 0; mf < 4; ++mf)
            #pragma unroll
            for (int nf = 0; nf < 2; ++nf)
                acc[mf][nf] = MFMA16(af[mf], bf[nf], acc[mf][nf]);
        __syncthreads();
    }

    // epilogue: 4 passes of 32 rows through LDS (fp32, padded 129)
    unsigned short* outu = (unsigned short*)outv;
    float* outf = (float*)outv;
    for (int p = 0; p < 4; ++p) {
        if (wr == (p >> 1)) {
            #pragma unroll
            for (int mh = 0; mh < 2; ++mh) {
                int mf = (p&1)*2 + mh;
                #pragma unroll
                for (int nf = 0; nf < 2; ++nf)
                    #pragma unroll
                    for (int r = 0; r < 4; ++r)
                        sm.epi[mh*16 + 4*g + r][wc*32 + nf*16 + qq] = acc[mf][nf][r]*scale;
            }
        }
        __syncthreads();
        if (MODE == 1) {
            #pragma unroll
            for (int i = 0; i < 8; ++i) {
                int c2 = i*16 + wave*2 + (lane>>5);
                int gr = rowoff + bt*128 + p*32 + (lane & 31);
                int bb = gr / posPer, pos = gr - bb*posPer;
                int hh = ctile*2 + (c2>>6), dh = c2 & 63;
                outu[((size_t)(bb*CH + hh)*64 + dh)*posPer + pos] = f2bf(sm.epi[lane&31][c2]);
            }
        } else {
            #pragma unroll
            for (int i = 0; i < 8; ++i) {
                int task = i*8 + wave;     // 0..63: (lr, ch)
                int lr = task >> 1, ch = task & 1;
                float val = sm.epi[lr][ch*64 + lane];
                int gr = rowoff + bt*128 + p*32 + lr;
                if (MODE == 2) {
                    outf[(size_t)gr*CD + ctile*128 + ch*64 + lane] = val;
                } else {
                    int bb = gr / posPer, pos = gr - bb*posPer;
                    int hh = ctile*2 + ch;
                    outu[((size_t)(bb*CH + hh)*posPer + pos)*64 + lane] = f2bf(val);
                }
            }
        }
        __syncthreads();
    }
}

// ---- scores pass A: per-(b,h,t,keycol) partial max / sumexp over 24 query rows ----
__global__ __launch_bounds__(256) void scores_a_kernel(
    const unsigned short* __restrict__ qp, const unsigned short* __restrict__ kp,
    const unsigned int* __restrict__ maskb,
    float* __restrict__ pmax, float* __restrict__ psum)
{
    __shared__ float S[CTN][65];
    int mt = blockIdx.x;
    int h = blockIdx.y, b = blockIdx.z;
    int lane = threadIdx.x & 63, wave = threadIdx.x >> 6;
    const unsigned short* qbase = qp + (size_t)(b*CH + h)*CTN*64;
    const unsigned short* kbase = kp + (size_t)(b*CH + h)*CTL*64;
    int koff = 8*(lane>>4);
    f32x4 acc[3][4] = {};
    for (int k0 = 0; k0 < 64; k0 += 32) {
        bf16x8 bfr[4];
        #pragma unroll
        for (int cf = 0; cf < 4; ++cf)
            bfr[cf] = ldbf8(kbase + (size_t)(mt*64 + cf*16 + (lane&15))*64 + k0 + koff);
        #pragma unroll
        for (int i = 0; i < 3; ++i) {
            int rt = wave + 4*i;
            if (rt < 9) {
                bf16x8 a = ldbf8(qbase + (size_t)(rt*16 + (lane&15))*64 + k0 + koff);
                #pragma unroll
                for (int cf = 0; cf < 4; ++cf)
                    acc[i][cf] = MFMA16(a, bfr[cf], acc[i][cf]);
            }
        }
    }
    #pragma unroll
    for (int i = 0; i < 3; ++i) {
        int rt = wave + 4*i;
        if (rt < 9) {
            #pragma unroll
            for (int cf = 0; cf < 4; ++cf)
                #pragma unroll
                for (int r = 0; r < 4; ++r)
                    S[rt*16 + 4*(lane>>4) + r][cf*16 + (lane&15)] = acc[i][cf][r];
        }
    }
    __syncthreads();
    int mg0 = mt*64;
    for (int task = threadIdx.x; task < CT*64; task += 256) {
        int t = task >> 6, ml = task & 63;
        int mg = mg0 + ml;
        unsigned w = maskb[(size_t)t*CTL + mg];
        float mx = -INFINITY;
        float sv[24];
        #pragma unroll
        for (int i = 0; i < 24; ++i) {
            float s = ((w >> i) & 1u) ? -INFINITY : S[t*24 + i][ml];
            sv[i] = s;
            mx = fmaxf(mx, s);
        }
        float sum = 0.f;
        if (mx > -INFINITY) {
            #pragma unroll
            for (int i = 0; i < 24; ++i)
                if (sv[i] > -INFINITY) sum += __expf(sv[i] - mx);
        }
        size_t idx = ((size_t)(b*CH + h)*CT + t)*CTL + mg;
        pmax[idx] = mx; psum[idx] = sum;
    }
}

// ---- combine partial softmax stats across heads ----
__global__ void combine_kernel(const float* __restrict__ pmax, const float* __restrict__ psum,
                               float* __restrict__ gmax, float* __restrict__ gsum){
    size_t i = (size_t)blockIdx.x*blockDim.x + threadIdx.x;
    if (i >= (size_t)CB*CT*CTL) return;
    int m = (int)(i % CTL);
    size_t bt = i / CTL;
    int t = (int)(bt % CT), b = (int)(bt / CT);
    float pm[CH], ps[CH];
    float mx = -INFINITY;
    #pragma unroll
    for (int h = 0; h < CH; ++h) {
        size_t idx = ((size_t)(b*CH + h)*CT + t)*CTL + m;
        pm[h] = pmax[idx]; ps[h] = psum[idx];
        mx = fmaxf(mx, pm[h]);
    }
    float s = 0.f;
    if (mx > -INFINITY) {
        #pragma unroll
        for (int h = 0; h < CH; ++h)
            if (pm[h] > -INFINITY) s += ps[h]*__expf(pm[h] - mx);
    }
    gmax[i] = mx; gsum[i] = s;
}

// ---- fused pass B + PV: 9 waves, one 16-row tile per wave, 1 barrier/tile ----
__global__ __launch_bounds__(576, 5) void fused_bpv(
    const unsigned short* __restrict__ qp, const unsigned short* __restrict__ kp,
    const unsigned short* __restrict__ vpT,
    const unsigned int* __restrict__ maskb,
    const float* __restrict__ gmax, const float* __restrict__ gsum,
    float* __restrict__ avis, float* __restrict__ pvpart, float* __restrict__ rowpart)
{
    __shared__ struct {
        unsigned short abf[9][16][68];     // per-wave a-tile, no cross-wave reads
        float gs[2][CT][64];               // double-buffered stats
        float gi[2][CT][64];
        unsigned int mb[2][CT][64];
    } sm;                                   // 28800 B

    int ms = blockIdx.x;                   // 8 slices of 768 keys
    int h = blockIdx.y, b = blockIdx.z;
    int bh = b*CH + h;
    int tid = threadIdx.x;
    int lane = tid & 63, wave = tid >> 6;  // wave = row-tile (0..8)
    int qq = lane & 15, g = lane >> 4;
    int koff = 8*g;

    const unsigned short* qbase = qp + (size_t)bh*CTN*64;
    const unsigned short* kbase = kp + (size_t)bh*CTL*64;
    const unsigned short* vb    = vpT + (size_t)bh*64*CTL;

    bf16x8 qf[2];
    #pragma unroll
    for (int x = 0; x < 2; ++x)
        qf[x] = ldbf8(qbase + (size_t)(wave*16 + qq)*64 + x*32 + koff);

    // loop-invariant per-r row -> (t, bit) mapping
    int trow[4], rbit[4];
    #pragma unroll
    for (int r = 0; r < 4; ++r) {
        int row = wave*16 + 4*g + r;
        trow[r] = row / 24;
        rbit[r] = row - trow[r]*24;
    }

    f32x4 pv[4] = {};
    float rs[4] = {};

    auto stage = [&](int buf, int mg0){
        for (int e = tid; e < CT*64; e += 576) {
            int t = e >> 6, c = e & 63;
            size_t gix = ((size_t)b*CT + t)*CTL + mg0 + c;
            float gm = gmax[gix], gv = gsum[gix];
            sm.gs[buf][t][c] = gm;
            sm.gi[buf][t][c] = (gv > 0.f) ? 1.f/gv : 0.f;
            sm.mb[buf][t][c] = maskb[(size_t)t*CTL + mg0 + c];
        }
    };
    stage(0, ms*768);
    __syncthreads();

    for (int mt = 0; mt < 12; ++mt) {
        int mg0 = ms*768 + mt*64;
        int cur = mt & 1;
        // QK^T (K fragments loaded per x-half to limit register pressure)
        f32x4 sacc[4] = {};
        #pragma unroll
        for (int x = 0; x < 2; ++x) {
            bf16x8 kf[4];
            #pragma unroll
            for (int cf = 0; cf < 4; ++cf)
                kf[cf] = ldbf8(kbase + (size_t)(mg0 + cf*16 + qq)*64 + x*32 + koff);
            #pragma unroll
            for (int cf = 0; cf < 4; ++cf)
                sacc[cf] = MFMA16(qf[x], kf[cf], sacc[cf]);
        }
        // softmax + avis + abf + rowsum
        #pragma unroll
        for (int r = 0; r < 4; ++r) {
            int lrow = 4*g + r;
            int grow = wave*16 + lrow;
            int t = trow[r], rb = rbit[r];
            float rsum = 0.f;
            #pragma unroll
            for (int cf = 0; cf < 4; ++cf) {
                int col = cf*16 + qq;
                float a = 0.f;
                if (!((sm.mb[cur][t][col] >> rb) & 1u))
                    a = __expf(sacc[cf][r] - sm.gs[cur][t][col]) * sm.gi[cur][t][col];
                avis[((size_t)bh*CTN + grow)*CTL + mg0 + col] = a;
                sm.abf[wave][lrow][col] = f2bf(a);
                rsum += a;
            }
            rs[r] += rsum;
        }
        // stage stats for next tile into the other buffer
        if (mt < 11) stage(cur ^ 1, mg0 + 64);
        // PV from own abf rows (wave-local, no barrier needed)
        #pragma unroll
        for (int x = 0; x < 2; ++x) {
            bf16x8 bv[4];
            #pragma unroll
            for (int cf = 0; cf < 4; ++cf)
                bv[cf] = ldbf8(vb + (size_t)(cf*16 + qq)*CTL + mg0 + x*32 + koff);
            bf16x8 af = *(const bf16x8*)&sm.abf[wave][qq][x*32 + koff];
            #pragma unroll
            for (int cf = 0; cf < 4; ++cf)
                pv[cf] = MFMA16(af, bv[cf], pv[cf]);
        }
        __syncthreads();   // one barrier per tile: stats buffer rotation
    }

    // rowsum: reduce over the 16 lanes (qq) sharing each row
    #pragma unroll
    for (int r = 0; r < 4; ++r) {
        float s = rs[r];
        s += __shfl_xor(s, 1); s += __shfl_xor(s, 2);
        s += __shfl_xor(s, 4); s += __shfl_xor(s, 8);
        if (qq == 0)
            rowpart[(size_t)ms*(CB*CH*CTN) + (size_t)bh*CTN + wave*16 + 4*g + r] = s;
    }
    // PV partial write
    float* pb = pvpart + (size_t)(ms*64 + bh)*CTN*64;
    #pragma unroll
    for (int cf = 0; cf < 4; ++cf)
        #pragma unroll
        for (int r = 0; r < 4; ++r)
            pb[(wave*16 + 4*g + r)*64 + cf*16 + qq] = pv[cf][r];
}

// ---- reduce rowsum partials over ms ----
__global__ void rowsum_kernel(const float* __restrict__ rowpart, float* __restrict__ rowsum){
    int i = blockIdx.x*blockDim.x + threadIdx.x;
    if (i >= CB*CH*CTN) return;
    float s = 0.f;
    #pragma unroll
    for (int ms = 0; ms < 8; ++ms) s += rowpart[(size_t)ms*(CB*CH*CTN) + i];
    rowsum[i] = s;
}

// ---- reduce PV partials, renormalize, write oh bf16 ----
__global__ void pv_reduce_kernel(const float* __restrict__ pvpart, const float* __restrict__ rowsum,
                                 unsigned short* __restrict__ oh){
    int idx = blockIdx.x*blockDim.x + threadIdx.x;
    if (idx >= CB*CH*CTN*64) return;
    float s = 0.f;
    #pragma unroll
    for (int ms = 0; ms < 8; ++ms)
        s += pvpart[(size_t)ms*(CB*CH*CTN*64) + idx];
    int col = idx & 63;
    int rowbh = idx >> 6;
    int row = rowbh % CTN, bh = rowbh / CTN;
    float inv = 1.f / (rowsum[rowbh] + CEPS);
    int b = bh >> 3, h = bh & 7;
    oh[((size_t)b*CTN + row)*CD + h*64 + col] = f2bf(s*inv);
}

extern "C" void kernel_launch(void* const* d_in, const int* in_sizes, int n_in,
                              void* d_out, int out_size, void* d_ws, size_t ws_size,
                              hipStream_t stream)
{
    const float* q    = (const float*)d_in[0];
    const float* k    = (const float*)d_in[1];
    const float* v    = (const float*)d_in[2];
    const int*   mask = (const int*)  d_in[3];
    const float* Wq   = (const float*)d_in[4];
    const float* Wk   = (const float*)d_in[5];
    const float* Wv   = (const float*)d_in[6];
    const float* Wo   = (const float*)d_in[7];

    float* out0 = (float*)d_out;
    float* avis = out0 + (size_t)CB*CTN*CD;

    char* p = (char*)d_ws;
    auto alloc = [&](size_t bytes) -> char* {
        char* r = p; p += (bytes + 255) & ~(size_t)255; return r;
    };
    unsigned short* Wq_bf = (unsigned short*)alloc((size_t)CD*CD*2);
    unsigned short* Wk_bf = (unsigned short*)alloc((size_t)CD*CD*2);
    unsigned short* Wv_bf = (unsigned short*)alloc((size_t)CD*CD*2);
    unsigned short* Wo_bf = (unsigned short*)alloc((size_t)CD*CD*2);
    unsigned short* qp    = (unsigned short*)alloc((size_t)CB*CH*CTN*64*2);
    unsigned short* kp    = (unsigned short*)alloc((size_t)CB*CH*CTL*64*2);
    unsigned short* vpT   = (unsigned short*)alloc((size_t)CB*CH*64*CTL*2);
    // S region (18.87 MB), time-multiplexed:
    //   proj phase:  xbf chunk buffer (16.78 MB)
    //   scores A:    pmax (9.44) | psum (9.44)
    //   fused_bpv:   pvpart (18.87) aliases dead pmax/psum
    char* S = alloc((size_t)CB*CH*CT*CTL*4*2);
    unsigned short* xbf = (unsigned short*)S;
    float* pmax   = (float*)S;
    float* psum   = (float*)(S + (size_t)CB*CH*CT*CTL*4);
    float* pvpart = (float*)S;
    float* gmax   = (float*)alloc((size_t)CB*CT*CTL*4);
    float* gsum   = (float*)alloc((size_t)CB*CT*CTL*4);
    unsigned int* maskb = (unsigned int*)alloc((size_t)CT*CTL*4);
    float* rowpart = (float*)alloc((size_t)8*CB*CH*CTN*4);
    float* rowsum  = (float*)alloc((size_t)CB*CH*CTN*4);
    unsigned short* oh = (unsigned short*)alloc((size_t)CB*CTN*CD*2);

    // 1. weights -> bf16; mask -> bitwords
    cvt_w_kernel<<<(4*CD*CD + 255)/256, 256, 0, stream>>>(Wq, Wk, Wv, Wo,
                                                          Wq_bf, Wk_bf, Wv_bf, Wo_bf);
    maskb_kernel<<<(CT*CTL + 255)/256, 256, 0, stream>>>(mask, maskb);
    // 2. q projection
    cvt_x_kernel<<<(CB*CTN*CD/8 + 255)/256, 256, 0, stream>>>(q, xbf, CB*CTN*CD/8);
    gemm_m97<0><<<dim3(4, CB*CTN/128), 512, 0, stream>>>(xbf, Wq_bf, qp, CTN, 0, 0.125f);
    // 3. k projection, 3 chunks of 16384 rows (keeps per-XCD L2 footprint small)
    for (int c = 0; c < 3; ++c) {
        cvt_x_kernel<<<(16384*CD/8 + 255)/256, 256, 0, stream>>>(k + (size_t)c*16384*CD, xbf, 16384*CD/8);
        gemm_m97<0><<<dim3(4, 128), 512, 0, stream>>>(xbf, Wk_bf, kp, CTL, c*16384, 1.0f);
    }
    // 4. v projection (transposed output), 3 chunks
    for (int c = 0; c < 3; ++c) {
        cvt_x_kernel<<<(16384*CD/8 + 255)/256, 256, 0, stream>>>(v + (size_t)c*16384*CD, xbf, 16384*CD/8);
        gemm_m97<1><<<dim3(4, 128), 512, 0, stream>>>(xbf, Wv_bf, vpT, CTL, c*16384, 1.0f);
    }
    // 5. scores pass A
    scores_a_kernel<<<dim3(CTL/64, CH, CB), 256, 0, stream>>>(qp, kp, maskb, pmax, psum);
    // 6. combine across heads
    combine_kernel<<<((CB*CT*CTL) + 255)/256, 256, 0, stream>>>(pmax, psum, gmax, gsum);
    // 7. fused pass B + PV
    fused_bpv<<<dim3(8, CH, CB), 576, 0, stream>>>(qp, kp, vpT, maskb, gmax, gsum,
                                                   avis, pvpart, rowpart);
    // 8. reduce rowsums and PV partials
    rowsum_kernel<<<((CB*CH*CTN) + 255)/256, 256, 0, stream>>>(rowpart, rowsum);
    pv_reduce_kernel<<<((CB*CH*CTN*64) + 255)/256, 256, 0, stream>>>(pvpart, rowsum, oh);
    // 9. output projection
    gemm_m97<2><<<dim3(4, CB*CTN/128), 512, 0, stream>>>(oh, Wo_bf, out0, CD, 0, 1.0f);
}